// Round 4
// baseline (700.488 us; speedup 1.0000x reference)
//
#include <hip/hip_runtime.h>

#define CH 64
#define HH 128
#define WW 128
#define BB 8
#define HW (HH*WW)

// ---------------- BN stats: per-channel partial sums (atomics) ----------------
__global__ __launch_bounds__(256) void k_stats(const float* __restrict__ xL,
                                               const float* __restrict__ xR,
                                               float* __restrict__ sums) {
  int blk = blockIdx.x;                 // 512 blocks: img(2) x c(64) x slice(4)
  int img = blk >> 8, c = (blk >> 2) & 63, s = blk & 3;
  const float* x = img ? xR : xL;
  float sm = 0.f, sq = 0.f;
  for (int n = 2*s; n < 2*s+2; ++n) {
    const float4* p = (const float4*)(x + ((size_t)(n*64+c))*HW);
    for (int i = threadIdx.x; i < 4096; i += 256) {
      float4 v = p[i];
      sm += (v.x+v.y)+(v.z+v.w);
      sq += (v.x*v.x+v.y*v.y)+(v.z*v.z+v.w*v.w);
    }
  }
  #pragma unroll
  for (int o = 32; o > 0; o >>= 1) { sm += __shfl_down(sm, o); sq += __shfl_down(sq, o); }
  __shared__ float rs[2][4];
  int wid = threadIdx.x >> 6;
  if ((threadIdx.x & 63) == 0) { rs[0][wid] = sm; rs[1][wid] = sq; }
  __syncthreads();
  if (threadIdx.x == 0) {
    sm = (rs[0][0]+rs[0][1])+(rs[0][2]+rs[0][3]);
    sq = (rs[1][0]+rs[1][1])+(rs[1][2]+rs[1][3]);
    atomicAdd(&sums[(img*64+c)*2+0], sm);
    atomicAdd(&sums[(img*64+c)*2+1], sq);
  }
}

__global__ __launch_bounds__(128) void k_finalize(const float* __restrict__ sums,
                                                  const float* __restrict__ gamma,
                                                  const float* __restrict__ beta,
                                                  float* __restrict__ ss) {
  int t = threadIdx.x;
  if (t < 128) {
    int c = t & 63;
    float sm = sums[t*2], sq = sums[t*2+1];
    float mean = sm * (1.f/131072.f);
    float var  = sq * (1.f/131072.f) - mean*mean;
    float scale = gamma[c] * rsqrtf(var + 1e-5f);
    ss[t*2+0] = scale;
    ss[t*2+1] = beta[c] - mean*scale;
  }
}

// ---------------- grouped 3x3 conv, pad=1 ----------------
// MODE 0: in = x, apply BN(ss) to input, LeakyReLU(0.1) epilogue -> out
// MODE 1: in = y1 (plain), epilogue adds BN(xres) residual -> out
template<int MODE>
__global__ __launch_bounds__(256) void k_conv(const float* __restrict__ in,
                                              const float* __restrict__ xres,
                                              const float* __restrict__ w,
                                              const float* __restrict__ bias,
                                              const float* __restrict__ ss,
                                              float* __restrict__ out) {
  __shared__ float in_t[16][18][20];
  __shared__ float w_t[16][192];   // [oc][ic*12 + k]
  int tile = blockIdx.x, g = blockIdx.y, n = blockIdx.z;
  int x0 = (tile & 7) << 4, y0 = (tile >> 3) << 4;
  int t = threadIdx.x;

  for (int idx = t; idx < 2304; idx += 256) {
    int oc = idx/144, r = idx%144, ic = r/9, k = r%9;
    w_t[oc][ic*12+k] = w[(g*16+oc)*144 + r];
  }
  for (int idx = t; idx < 16*18*18; idx += 256) {
    int ic = idx/324, r2 = idx%324, ry = r2/18, rx = r2%18;
    int gy = y0-1+ry, gx = x0-1+rx;
    int c = g*16+ic;
    float v = 0.f;
    if (gy >= 0 && gy < 128 && gx >= 0 && gx < 128) {
      v = in[((size_t)(n*64+c)*128 + gy)*128 + gx];
      if (MODE == 0) v = v*ss[c*2] + ss[c*2+1];
    }
    in_t[ic][ry][rx] = v;
  }
  __syncthreads();

  int oc = t >> 4, sub = t & 15;
  int sy = (sub >> 2) << 2, sx = (sub & 3) << 2;
  float acc[4][4];
  float bv = bias[g*16+oc];
  #pragma unroll
  for (int i = 0; i < 4; ++i)
    #pragma unroll
    for (int j = 0; j < 4; ++j) acc[i][j] = bv;

  for (int ic = 0; ic < 16; ++ic) {
    float win[6][6];
    #pragma unroll
    for (int r = 0; r < 6; ++r) {
      const float4 wa = *(const float4*)&in_t[ic][sy+r][sx];
      const float2 wb = *(const float2*)&in_t[ic][sy+r][sx+4];
      win[r][0]=wa.x; win[r][1]=wa.y; win[r][2]=wa.z; win[r][3]=wa.w;
      win[r][4]=wb.x; win[r][5]=wb.y;
    }
    const float4 w0 = *(const float4*)&w_t[oc][ic*12];
    const float4 w1 = *(const float4*)&w_t[oc][ic*12+4];
    const float  w8 = w_t[oc][ic*12+8];
    float wv[9] = {w0.x,w0.y,w0.z,w0.w,w1.x,w1.y,w1.z,w1.w,w8};
    #pragma unroll
    for (int i = 0; i < 4; ++i)
      #pragma unroll
      for (int j = 0; j < 4; ++j) {
        float a = acc[i][j];
        #pragma unroll
        for (int ky = 0; ky < 3; ++ky)
          #pragma unroll
          for (int kx = 0; kx < 3; ++kx)
            a = fmaf(win[i+ky][j+kx], wv[ky*3+kx], a);
        acc[i][j] = a;
      }
  }

  int c = g*16+oc;
  #pragma unroll
  for (int i = 0; i < 4; ++i) {
    int oy = y0+sy+i;
    size_t rowbase = ((size_t)(n*64+c)*128 + oy)*128;
    #pragma unroll
    for (int j = 0; j < 4; ++j) {
      int ox = x0+sx+j;
      float v = acc[i][j];
      if (MODE == 0) { v = v > 0.f ? v : 0.1f*v; }
      else           { v += xres[rowbase+ox]*ss[c*2] + ss[c*2+1]; }
      out[rowbase+ox] = v;
    }
  }
}

// ---------------- grouped 1x1 conv + row-mean subtract (in-place) ----------------
__global__ __launch_bounds__(256) void k_qk(float* __restrict__ y2,
                                            const float* __restrict__ w,
                                            const float* __restrict__ bias) {
  __shared__ float row[64][128];
  __shared__ float wt[64][16];
  __shared__ float bt[64];
  int b = blockIdx.x >> 7, h = blockIdx.x & 127;
  int t = threadIdx.x;
  for (int idx = t; idx < 1024; idx += 256) wt[idx>>4][idx&15] = w[idx];
  if (t < 64) bt[t] = bias[t];
  __syncthreads();
  size_t base = ((size_t)(b*64)*128 + h)*128;   // + c*HW + u
  for (int idx = t; idx < 2048; idx += 256) {
    int c = idx >> 5, u4 = (idx & 31) << 2;
    *(float4*)&row[c][u4] = *(const float4*)&y2[base + (size_t)c*HW + u4];
  }
  __syncthreads();
  int u0 = (t & 31) << 2, oc0 = (t >> 5) << 3;
  int g = oc0 >> 4;
  float acc[8][4];
  #pragma unroll
  for (int j = 0; j < 8; ++j) {
    float b0 = bt[oc0+j];
    acc[j][0]=b0; acc[j][1]=b0; acc[j][2]=b0; acc[j][3]=b0;
  }
  for (int ic = 0; ic < 16; ++ic) {
    const float4 iv = *(const float4*)&row[g*16+ic][u0];
    #pragma unroll
    for (int j = 0; j < 8; ++j) {
      float wv = wt[oc0+j][ic];
      acc[j][0] = fmaf(wv, iv.x, acc[j][0]);
      acc[j][1] = fmaf(wv, iv.y, acc[j][1]);
      acc[j][2] = fmaf(wv, iv.z, acc[j][2]);
      acc[j][3] = fmaf(wv, iv.w, acc[j][3]);
    }
  }
  #pragma unroll
  for (int j = 0; j < 8; ++j) {
    float s = (acc[j][0]+acc[j][1])+(acc[j][2]+acc[j][3]);
    #pragma unroll
    for (int o = 16; o > 0; o >>= 1) s += __shfl_xor(s, o, 32);
    float mean = s * (1.f/128.f);
    float4 ov = make_float4(acc[j][0]-mean, acc[j][1]-mean, acc[j][2]-mean, acc[j][3]-mean);
    *(float4*)&y2[base + (size_t)(oc0+j)*HW + u0] = ov;
  }
}

// ---------------- PAM core: one block per (b,h) row ----------------
// ST[16384] swizzled score; QK[16384] Qs/Ks -> G -> xls/xrs; stats + scratch.
// ST[SW(v,u)] = score[u][v].  SW/SWQ map LOGICAL (row r, col c / quad q) -> physical.
__device__ __forceinline__ int SW(int r, int c) {
  return (r << 7) + (((c >> 2) ^ (r & 31)) << 2) + (c & 3);
}
__device__ __forceinline__ int SWQ(int r, int q) {
  return (r << 7) + ((q ^ (r & 31)) << 2);
}

__global__ __launch_bounds__(512) void k_pam(const float* __restrict__ Q,
                                             const float* __restrict__ K,
                                             const float* __restrict__ XL,
                                             const float* __restrict__ XR,
                                             float* __restrict__ outL,
                                             float* __restrict__ outR) {
  extern __shared__ float smp[];
  float* ST   = smp;
  float* QK   = smp + 16384;
  float* rmax = smp + 32768;
  float* rinv = rmax + 128;
  float* cmax = rmax + 256;
  float* cinv = rmax + 384;
  float* Vl   = rmax + 512;
  float* Vr   = rmax + 640;
  float* scr  = rmax + 768;
  float* pm  = scr;
  float* pl  = scr + 512;
  float* pm2 = scr + 1024;
  float* pl2 = scr + 1536;
  float* G   = QK;            // after Qs/Ks dead
  float* xls = QK;            // after G dead
  float* xrs = QK + 8192;

  int t = threadIdx.x;
  int b = blockIdx.x >> 7, h = blockIdx.x & 127;
  size_t qbase = ((size_t)(b*64)*128 + h)*128;   // + c*HW + u

  // ---- P0: load Q,K rows into QK as [c][u] (stride 128) ----
  for (int idx = t; idx < 2048; idx += 512) {
    int c = idx >> 5, u4 = (idx & 31) << 2;
    *(float4*)&QK[c*128 + u4]        = *(const float4*)&Q[qbase + (size_t)c*HW + u4];
    *(float4*)&QK[8192 + c*128 + u4] = *(const float4*)&K[qbase + (size_t)c*HW + u4];
  }
  __syncthreads();

  // ---- P1: score -> ST (swizzled), thread tile 4u x 8v ----
  {
    int u0 = (t & 31) << 2, v0 = (t >> 5) << 3;
    float a0[8], a1[8], a2[8], a3[8];
    #pragma unroll
    for (int j = 0; j < 8; ++j) { a0[j]=0.f; a1[j]=0.f; a2[j]=0.f; a3[j]=0.f; }
    for (int c = 0; c < 64; ++c) {
      const float4 qv = *(const float4*)&QK[c*128 + u0];
      const float4 k0 = *(const float4*)&QK[8192 + c*128 + v0];
      const float4 k1 = *(const float4*)&QK[8192 + c*128 + v0 + 4];
      float kk[8] = {k0.x,k0.y,k0.z,k0.w,k1.x,k1.y,k1.z,k1.w};
      #pragma unroll
      for (int j = 0; j < 8; ++j) {
        float kv = kk[j];
        a0[j] = fmaf(qv.x, kv, a0[j]);
        a1[j] = fmaf(qv.y, kv, a1[j]);
        a2[j] = fmaf(qv.z, kv, a2[j]);
        a3[j] = fmaf(qv.w, kv, a3[j]);
      }
    }
    __syncthreads();
    #pragma unroll
    for (int j = 0; j < 8; ++j) {
      int r = v0 + j;
      *(float4*)&ST[SWQ(r, u0 >> 2)] = make_float4(a0[j], a1[j], a2[j], a3[j]);
    }
  }
  __syncthreads();

  // ---- P2: row stats (over v, fixed u) + col stats (over u, fixed v) ----
  {
    int u = t & 127, q = t >> 7, vb = q << 5;
    float m = -1e30f;
    for (int v = vb; v < vb+32; ++v) m = fmaxf(m, ST[SW(v, u)]);
    float l = 0.f;
    for (int v = vb; v < vb+32; ++v) l += __expf(ST[SW(v, u)] - m);
    pm[t] = m; pl[t] = l;
    int r = u;           // col task: scan row r of ST over u-chunk
    float m2 = -1e30f;
    for (int k = (vb >> 2); k < (vb >> 2) + 8; ++k) {
      const float4 x4 = *(const float4*)&ST[SWQ(r, k)];
      m2 = fmaxf(m2, fmaxf(fmaxf(x4.x, x4.y), fmaxf(x4.z, x4.w)));
    }
    float l2 = 0.f;
    for (int k = (vb >> 2); k < (vb >> 2) + 8; ++k) {
      const float4 x4 = *(const float4*)&ST[SWQ(r, k)];
      l2 += (__expf(x4.x-m2)+__expf(x4.y-m2)) + (__expf(x4.z-m2)+__expf(x4.w-m2));
    }
    pm2[t] = m2; pl2[t] = l2;
  }
  __syncthreads();
  if (t < 256) {
    int u = t & 127;
    const float* PM = (t < 128) ? pm : pm2;
    const float* PL = (t < 128) ? pl : pl2;
    float m = fmaxf(fmaxf(PM[u], PM[128+u]), fmaxf(PM[256+u], PM[384+u]));
    float l = PL[u]*__expf(PM[u]-m) + PL[128+u]*__expf(PM[128+u]-m)
            + PL[256+u]*__expf(PM[256+u]-m) + PL[384+u]*__expf(PM[384+u]-m);
    if (t < 128) { rmax[u] = m; rinv[u] = 1.f/l; }
    else         { cmax[u] = m; cinv[u] = 1.f/l; }
  }
  __syncthreads();

  // ---- P3a: G[u][v] = m_relax(M_lr)[u][v] ----
  {
    int v = t & 127, q = t >> 7, a0i = q << 5;
    #define EF(a) (((a) < 0 || (a) >= 128) ? 0.f : __expf(ST[SW((a), v)] - cmax[(a)]) * cinv[(a)])
    float e0 = EF(a0i-2), e1 = EF(a0i-1), e2 = EF(a0i), e3 = EF(a0i+1);
    #pragma unroll
    for (int k = 0; k < 32; ++k) {
      int u = a0i + k;
      float e4 = EF(u+2);
      G[SW(u, v)] = ((e0+e1)+(e2+e3)) + e4;
      e0 = e1; e1 = e2; e2 = e3; e3 = e4;
    }
    #undef EF
  }
  __syncthreads();

  // ---- P3b: V partials ----
  {
    int u = t & 127, q = t >> 7, vb = q << 5;
    float rmm[5], rii[5];
    #pragma unroll
    for (int d = 0; d < 5; ++d) {
      int uu = u - 2 + d;
      bool ok = (uu >= 0 && uu < 128);
      rmm[d] = ok ? rmax[uu] : 1e30f;
      rii[d] = ok ? rinv[uu] : 0.f;
    }
    float accL = 0.f, accR = 0.f;
    for (int v = vb; v < vb+32; ++v) {
      float s = ST[SW(v, u)];
      float clr = __expf(s - cmax[v]) * cinv[v];
      float R = __expf(s - rmm[2]) * rii[2];
      if (u >= 2)   R += __expf(ST[SW(v, u-2)] - rmm[0]) * rii[0];
      if (u >= 1)   R += __expf(ST[SW(v, u-1)] - rmm[1]) * rii[1];
      if (u <= 126) R += __expf(ST[SW(v, u+1)] - rmm[3]) * rii[3];
      if (u <= 125) R += __expf(ST[SW(v, u+2)] - rmm[4]) * rii[4];
      accL += R * clr;
      float g   = G[SW(u, v)];
      float mrl = __expf(ST[SW(u, v)] - rmax[v]) * rinv[v];
      accR += g * mrl;
    }
    pm[t] = accL; pl[t] = accR;
  }
  __syncthreads();

  // ---- P3c finalize V + P4 load x rows (transposed [v][c], stride 64) ----
  if (t < 128) {
    float vsL = pm[t]+pm[128+t]+pm[256+t]+pm[384+t];
    float vsR = pl[t]+pl[128+t]+pl[256+t]+pl[384+t];
    Vl[t] = tanhf(5.f*vsL);
    Vr[t] = tanhf(5.f*vsR);
  }
  __syncthreads();
  for (int idx = t; idx < 2048; idx += 512) {
    int c = idx >> 5, w4 = (idx & 31) << 2;
    const float4 a = *(const float4*)&XL[qbase + (size_t)c*HW + w4];
    xls[(w4+0)*64+c] = a.x; xls[(w4+1)*64+c] = a.y; xls[(w4+2)*64+c] = a.z; xls[(w4+3)*64+c] = a.w;
    const float4 r4 = *(const float4*)&XR[qbase + (size_t)c*HW + w4];
    xrs[(w4+0)*64+c] = r4.x; xrs[(w4+1)*64+c] = r4.y; xrs[(w4+2)*64+c] = r4.z; xrs[(w4+3)*64+c] = r4.w;
  }
  __syncthreads();

  int ul = t & 63, c0 = (t >> 6) << 3;

  // ---- P5: out_left = xl*(1-Vl) + (M_rl @ xr)*Vl ----
  {
    float acc0[8], acc1[8];
    #pragma unroll
    for (int j = 0; j < 8; ++j) { acc0[j]=0.f; acc1[j]=0.f; }
    float rm0 = rmax[ul], ri0 = rinv[ul], rm1 = rmax[ul+64], ri1 = rinv[ul+64];
    for (int v = 0; v < 128; ++v) {
      float m0 = __expf(ST[SW(v, ul)]    - rm0) * ri0;
      float m1 = __expf(ST[SW(v, ul+64)] - rm1) * ri1;
      const float4 xa = *(const float4*)&xrs[v*64 + c0];
      const float4 xb = *(const float4*)&xrs[v*64 + c0 + 4];
      acc0[0]=fmaf(m0,xa.x,acc0[0]); acc0[1]=fmaf(m0,xa.y,acc0[1]);
      acc0[2]=fmaf(m0,xa.z,acc0[2]); acc0[3]=fmaf(m0,xa.w,acc0[3]);
      acc0[4]=fmaf(m0,xb.x,acc0[4]); acc0[5]=fmaf(m0,xb.y,acc0[5]);
      acc0[6]=fmaf(m0,xb.z,acc0[6]); acc0[7]=fmaf(m0,xb.w,acc0[7]);
      acc1[0]=fmaf(m1,xa.x,acc1[0]); acc1[1]=fmaf(m1,xa.y,acc1[1]);
      acc1[2]=fmaf(m1,xa.z,acc1[2]); acc1[3]=fmaf(m1,xa.w,acc1[3]);
      acc1[4]=fmaf(m1,xb.x,acc1[4]); acc1[5]=fmaf(m1,xb.y,acc1[5]);
      acc1[6]=fmaf(m1,xb.z,acc1[6]); acc1[7]=fmaf(m1,xb.w,acc1[7]);
    }
    float vl0 = Vl[ul], vl1 = Vl[ul+64];
    #pragma unroll
    for (int j = 0; j < 8; ++j) {
      size_t o0 = qbase + (size_t)(c0+j)*HW + ul;
      outL[o0]    = XL[o0]   *(1.f-vl0) + acc0[j]*vl0;
      outL[o0+64] = XL[o0+64]*(1.f-vl1) + acc1[j]*vl1;
    }
  }

  // ---- P6: out_right = xr*(1-Vr) + (M_lr @ xl)*Vr ----
  {
    float acc0[8], acc1[8];
    #pragma unroll
    for (int j = 0; j < 8; ++j) { acc0[j]=0.f; acc1[j]=0.f; }
    float cm0 = cmax[ul], ci0 = cinv[ul], cm1 = cmax[ul+64], ci1 = cinv[ul+64];
    for (int vq = 0; vq < 32; ++vq) {
      const float4 s0 = *(const float4*)&ST[SWQ(ul,    vq)];
      const float4 s1 = *(const float4*)&ST[SWQ(ul+64, vq)];
      float sv0[4] = {s0.x, s0.y, s0.z, s0.w};
      float sv1[4] = {s1.x, s1.y, s1.z, s1.w};
      // SWQ(r, q) addresses LOGICAL quad q -> these 4 elements are columns 4*vq..4*vq+3
      int vbase = vq << 2;
      #pragma unroll
      for (int k = 0; k < 4; ++k) {
        float m0 = __expf(sv0[k] - cm0) * ci0;
        float m1 = __expf(sv1[k] - cm1) * ci1;
        const float4 xa0 = *(const float4*)&xls[(vbase+k)*64 + c0];
        const float4 xb0 = *(const float4*)&xls[(vbase+k)*64 + c0 + 4];
        acc0[0]=fmaf(m0,xa0.x,acc0[0]); acc0[1]=fmaf(m0,xa0.y,acc0[1]);
        acc0[2]=fmaf(m0,xa0.z,acc0[2]); acc0[3]=fmaf(m0,xa0.w,acc0[3]);
        acc0[4]=fmaf(m0,xb0.x,acc0[4]); acc0[5]=fmaf(m0,xb0.y,acc0[5]);
        acc0[6]=fmaf(m0,xb0.z,acc0[6]); acc0[7]=fmaf(m0,xb0.w,acc0[7]);
        acc1[0]=fmaf(m1,xa0.x,acc1[0]); acc1[1]=fmaf(m1,xa0.y,acc1[1]);
        acc1[2]=fmaf(m1,xa0.z,acc1[2]); acc1[3]=fmaf(m1,xa0.w,acc1[3]);
        acc1[4]=fmaf(m1,xb0.x,acc1[4]); acc1[5]=fmaf(m1,xb0.y,acc1[5]);
        acc1[6]=fmaf(m1,xb0.z,acc1[6]); acc1[7]=fmaf(m1,xb0.w,acc1[7]);
      }
    }
    float vr0 = Vr[ul], vr1 = Vr[ul+64];
    #pragma unroll
    for (int j = 0; j < 8; ++j) {
      size_t o0 = qbase + (size_t)(c0+j)*HW + ul;
      outR[o0]    = XR[o0]   *(1.f-vr0) + acc0[j]*vr0;
      outR[o0+64] = XR[o0+64]*(1.f-vr1) + acc1[j]*vr1;
    }
  }
}

extern "C" void kernel_launch(void* const* d_in, const int* in_sizes, int n_in,
                              void* d_out, int out_size, void* d_ws, size_t ws_size,
                              hipStream_t stream) {
  const float* xL    = (const float*)d_in[0];
  const float* xR    = (const float*)d_in[1];
  const float* gamma = (const float*)d_in[2];
  const float* beta  = (const float*)d_in[3];
  const float* rw1   = (const float*)d_in[4];
  const float* rb1   = (const float*)d_in[5];
  const float* rw2   = (const float*)d_in[6];
  const float* rb2   = (const float*)d_in[7];
  const float* qw    = (const float*)d_in[8];
  const float* qb    = (const float*)d_in[9];
  const float* kw    = (const float*)d_in[10];
  const float* kb    = (const float*)d_in[11];
  float* out = (float*)d_out;
  char* ws = (char*)d_ws;

  const size_t BUF = (size_t)BB*CH*HW*4;   // 33,554,432 bytes
  float* y1   = (float*)(ws);
  float* y2L  = (float*)(ws + BUF);
  float* y2R  = (float*)(ws + 2*BUF);
  float* sums = (float*)(ws + 3*BUF);      // 256 floats
  float* ss   = sums + 256;                // 256 floats

  hipMemsetAsync(sums, 0, 1024, stream);
  k_stats<<<512, 256, 0, stream>>>(xL, xR, sums);
  k_finalize<<<1, 128, 0, stream>>>(sums, gamma, beta, ss);

  dim3 cg(64, 4, 8);
  k_conv<0><<<cg, 256, 0, stream>>>(xL, xL, rw1, rb1, ss,       y1);
  k_conv<1><<<cg, 256, 0, stream>>>(y1, xL, rw2, rb2, ss,       y2L);
  k_conv<0><<<cg, 256, 0, stream>>>(xR, xR, rw1, rb1, ss + 128, y1);
  k_conv<1><<<cg, 256, 0, stream>>>(y1, xR, rw2, rb2, ss + 128, y2R);

  k_qk<<<1024, 256, 0, stream>>>(y2L, qw, qb);
  k_qk<<<1024, 256, 0, stream>>>(y2R, kw, kb);

  const int SMEM = (16384 + 16384 + 768 + 2048) * 4;   // 142,336 B
  hipFuncSetAttribute((const void*)k_pam, hipFuncAttributeMaxDynamicSharedMemorySize, SMEM);
  k_pam<<<1024, 512, SMEM, stream>>>(y2L, y2R, xL, xR, out, out + (size_t)BB*CH*HW);
}

// Round 5
// 612.416 us; speedup vs baseline: 1.1438x; 1.1438x over previous
//
#include <hip/hip_runtime.h>

#define CH_N 64
#define HH 128
#define WW 128
#define BB 8
#define HW (HH*WW)

// ---------------- BN stats: per-channel partial sums (atomics) ----------------
__global__ __launch_bounds__(256) void k_stats(const float* __restrict__ xL,
                                               const float* __restrict__ xR,
                                               float* __restrict__ sums) {
  int blk = blockIdx.x;                 // 512 blocks: img(2) x c(64) x slice(4)
  int img = blk >> 8, c = (blk >> 2) & 63, s = blk & 3;
  const float* x = img ? xR : xL;
  float sm = 0.f, sq = 0.f;
  for (int n = 2*s; n < 2*s+2; ++n) {
    const float4* p = (const float4*)(x + ((size_t)(n*64+c))*HW);
    for (int i = threadIdx.x; i < 4096; i += 256) {
      float4 v = p[i];
      sm += (v.x+v.y)+(v.z+v.w);
      sq += (v.x*v.x+v.y*v.y)+(v.z*v.z+v.w*v.w);
    }
  }
  #pragma unroll
  for (int o = 32; o > 0; o >>= 1) { sm += __shfl_down(sm, o); sq += __shfl_down(sq, o); }
  __shared__ float rs[2][4];
  int wid = threadIdx.x >> 6;
  if ((threadIdx.x & 63) == 0) { rs[0][wid] = sm; rs[1][wid] = sq; }
  __syncthreads();
  if (threadIdx.x == 0) {
    sm = (rs[0][0]+rs[0][1])+(rs[0][2]+rs[0][3]);
    sq = (rs[1][0]+rs[1][1])+(rs[1][2]+rs[1][3]);
    atomicAdd(&sums[(img*64+c)*2+0], sm);
    atomicAdd(&sums[(img*64+c)*2+1], sq);
  }
}

__global__ __launch_bounds__(128) void k_finalize(const float* __restrict__ sums,
                                                  const float* __restrict__ gamma,
                                                  const float* __restrict__ beta,
                                                  float* __restrict__ ss) {
  int t = threadIdx.x;
  if (t < 128) {
    int c = t & 63;
    float sm = sums[t*2], sq = sums[t*2+1];
    float mean = sm * (1.f/131072.f);
    float var  = sq * (1.f/131072.f) - mean*mean;
    float scale = gamma[c] * rsqrtf(var + 1e-5f);
    ss[t*2+0] = scale;
    ss[t*2+1] = beta[c] - mean*scale;
  }
}

// ---------------- grouped 3x3 conv, pad=1 ----------------
template<int MODE>
__global__ __launch_bounds__(256) void k_conv(const float* __restrict__ in,
                                              const float* __restrict__ xres,
                                              const float* __restrict__ w,
                                              const float* __restrict__ bias,
                                              const float* __restrict__ ss,
                                              float* __restrict__ out) {
  __shared__ float in_t[16][18][20];
  __shared__ float w_t[16][192];   // [oc][ic*12 + k]
  int tile = blockIdx.x, g = blockIdx.y, n = blockIdx.z;
  int x0 = (tile & 7) << 4, y0 = (tile >> 3) << 4;
  int t = threadIdx.x;

  for (int idx = t; idx < 2304; idx += 256) {
    int oc = idx/144, r = idx%144, ic = r/9, k = r%9;
    w_t[oc][ic*12+k] = w[(g*16+oc)*144 + r];
  }
  for (int idx = t; idx < 16*18*18; idx += 256) {
    int ic = idx/324, r2 = idx%324, ry = r2/18, rx = r2%18;
    int gy = y0-1+ry, gx = x0-1+rx;
    int c = g*16+ic;
    float v = 0.f;
    if (gy >= 0 && gy < 128 && gx >= 0 && gx < 128) {
      v = in[((size_t)(n*64+c)*128 + gy)*128 + gx];
      if (MODE == 0) v = v*ss[c*2] + ss[c*2+1];
    }
    in_t[ic][ry][rx] = v;
  }
  __syncthreads();

  int oc = t >> 4, sub = t & 15;
  int sy = (sub >> 2) << 2, sx = (sub & 3) << 2;
  float acc[4][4];
  float bv = bias[g*16+oc];
  #pragma unroll
  for (int i = 0; i < 4; ++i)
    #pragma unroll
    for (int j = 0; j < 4; ++j) acc[i][j] = bv;

  for (int ic = 0; ic < 16; ++ic) {
    float win[6][6];
    #pragma unroll
    for (int r = 0; r < 6; ++r) {
      const float4 wa = *(const float4*)&in_t[ic][sy+r][sx];
      const float2 wb = *(const float2*)&in_t[ic][sy+r][sx+4];
      win[r][0]=wa.x; win[r][1]=wa.y; win[r][2]=wa.z; win[r][3]=wa.w;
      win[r][4]=wb.x; win[r][5]=wb.y;
    }
    const float4 w0 = *(const float4*)&w_t[oc][ic*12];
    const float4 w1 = *(const float4*)&w_t[oc][ic*12+4];
    const float  w8 = w_t[oc][ic*12+8];
    float wv[9] = {w0.x,w0.y,w0.z,w0.w,w1.x,w1.y,w1.z,w1.w,w8};
    #pragma unroll
    for (int i = 0; i < 4; ++i)
      #pragma unroll
      for (int j = 0; j < 4; ++j) {
        float a = acc[i][j];
        #pragma unroll
        for (int ky = 0; ky < 3; ++ky)
          #pragma unroll
          for (int kx = 0; kx < 3; ++kx)
            a = fmaf(win[i+ky][j+kx], wv[ky*3+kx], a);
        acc[i][j] = a;
      }
  }

  int c = g*16+oc;
  #pragma unroll
  for (int i = 0; i < 4; ++i) {
    int oy = y0+sy+i;
    size_t rowbase = ((size_t)(n*64+c)*128 + oy)*128;
    #pragma unroll
    for (int j = 0; j < 4; ++j) {
      int ox = x0+sx+j;
      float v = acc[i][j];
      if (MODE == 0) { v = v > 0.f ? v : 0.1f*v; }
      else           { v += xres[rowbase+ox]*ss[c*2] + ss[c*2+1]; }
      out[rowbase+ox] = v;
    }
  }
}

// ---------------- grouped 1x1 conv + row-mean subtract (in-place) ----------------
__global__ __launch_bounds__(256) void k_qk(float* __restrict__ y2,
                                            const float* __restrict__ w,
                                            const float* __restrict__ bias) {
  __shared__ float row[64][128];
  __shared__ float wt[64][16];
  __shared__ float bt[64];
  int b = blockIdx.x >> 7, h = blockIdx.x & 127;
  int t = threadIdx.x;
  for (int idx = t; idx < 1024; idx += 256) wt[idx>>4][idx&15] = w[idx];
  if (t < 64) bt[t] = bias[t];
  __syncthreads();
  size_t base = ((size_t)(b*64)*128 + h)*128;   // + c*HW + u
  for (int idx = t; idx < 2048; idx += 256) {
    int c = idx >> 5, u4 = (idx & 31) << 2;
    *(float4*)&row[c][u4] = *(const float4*)&y2[base + (size_t)c*HW + u4];
  }
  __syncthreads();
  int u0 = (t & 31) << 2, oc0 = (t >> 5) << 3;
  int g = oc0 >> 4;
  float acc[8][4];
  #pragma unroll
  for (int j = 0; j < 8; ++j) {
    float b0 = bt[oc0+j];
    acc[j][0]=b0; acc[j][1]=b0; acc[j][2]=b0; acc[j][3]=b0;
  }
  for (int ic = 0; ic < 16; ++ic) {
    const float4 iv = *(const float4*)&row[g*16+ic][u0];
    #pragma unroll
    for (int j = 0; j < 8; ++j) {
      float wv = wt[oc0+j][ic];
      acc[j][0] = fmaf(wv, iv.x, acc[j][0]);
      acc[j][1] = fmaf(wv, iv.y, acc[j][1]);
      acc[j][2] = fmaf(wv, iv.z, acc[j][2]);
      acc[j][3] = fmaf(wv, iv.w, acc[j][3]);
    }
  }
  #pragma unroll
  for (int j = 0; j < 8; ++j) {
    float s = (acc[j][0]+acc[j][1])+(acc[j][2]+acc[j][3]);
    #pragma unroll
    for (int o = 16; o > 0; o >>= 1) s += __shfl_xor(s, o, 32);
    float mean = s * (1.f/128.f);
    float4 ov = make_float4(acc[j][0]-mean, acc[j][1]-mean, acc[j][2]-mean, acc[j][3]-mean);
    *(float4*)&y2[base + (size_t)(oc0+j)*HW + u0] = ov;
  }
}

// ---------------- PAM core: one block per (b,h) row, 76.8 KB LDS -> 2 blk/CU ----
// ST[SW(v,u)] = score[u][v].  SW/SWQ map LOGICAL (row r, col c / quad q) -> physical.
__device__ __forceinline__ int SW(int r, int c) {
  return (r << 7) + (((c >> 2) ^ (r & 31)) << 2) + (c & 3);
}
__device__ __forceinline__ int SWQ(int r, int q) {
  return (r << 7) + ((q ^ (r & 31)) << 2);
}

__global__ __launch_bounds__(512, 4) void k_pam(const float* __restrict__ Q,
                                                const float* __restrict__ K,
                                                const float* __restrict__ XL,
                                                const float* __restrict__ XR,
                                                float* __restrict__ outL,
                                                float* __restrict__ outR) {
  extern __shared__ float smp[];
  float* ST   = smp;            // 16384 floats (64 KB), swizzled score
  float* CHB  = smp + 16384;    // 2048 floats (8 KB): QK chunks / x chunks / scratch
  float* rmax = smp + 18432;    // stats: 6*128 floats (3 KB)
  float* rinv = rmax + 128;
  float* cmax = rmax + 256;
  float* cinv = rmax + 384;
  float* Vl   = rmax + 512;
  float* Vr   = rmax + 640;
  float* pm   = CHB;            // P2/P3 partial scratch overlaps chunk buffer
  float* pl   = CHB + 512;
  float* pm2  = CHB + 1024;
  float* pl2  = CHB + 1536;

  int t = threadIdx.x;
  int b = blockIdx.x >> 7, h = blockIdx.x & 127;
  size_t qbase = ((size_t)(b*64)*128 + h)*128;   // + c*HW + u

  // ---- P1: score -> ST (swizzled), Q/K staged through 8 KB chunks of 8 ch ----
  {
    int u0 = (t & 31) << 2, v0 = (t >> 5) << 3;
    float a0[8], a1[8], a2[8], a3[8];
    #pragma unroll
    for (int j = 0; j < 8; ++j) { a0[j]=0.f; a1[j]=0.f; a2[j]=0.f; a3[j]=0.f; }
    int half = t >> 8;               // 0 = Q, 1 = K
    int cl_ld = (t >> 5) & 7;
    int u4_ld = (t & 31) << 2;
    const float* src = half ? K : Q;
    for (int cb = 0; cb < 8; ++cb) {
      __syncthreads();   // previous chunk fully consumed
      *(float4*)&CHB[half*1024 + cl_ld*128 + u4_ld] =
        *(const float4*)&src[qbase + (size_t)(cb*8 + cl_ld)*HW + u4_ld];
      __syncthreads();
      #pragma unroll
      for (int cl = 0; cl < 8; ++cl) {
        const float4 qv = *(const float4*)&CHB[cl*128 + u0];
        const float4 k0 = *(const float4*)&CHB[1024 + cl*128 + v0];
        const float4 k1 = *(const float4*)&CHB[1024 + cl*128 + v0 + 4];
        float kk[8] = {k0.x,k0.y,k0.z,k0.w,k1.x,k1.y,k1.z,k1.w};
        #pragma unroll
        for (int j = 0; j < 8; ++j) {
          float kv = kk[j];
          a0[j] = fmaf(qv.x, kv, a0[j]);
          a1[j] = fmaf(qv.y, kv, a1[j]);
          a2[j] = fmaf(qv.z, kv, a2[j]);
          a3[j] = fmaf(qv.w, kv, a3[j]);
        }
      }
    }
    #pragma unroll
    for (int j = 0; j < 8; ++j) {
      int r = v0 + j;
      *(float4*)&ST[SWQ(r, u0 >> 2)] = make_float4(a0[j], a1[j], a2[j], a3[j]);
    }
  }
  __syncthreads();

  // ---- P2: row stats (over v, fixed u) + col stats (over u, fixed v) ----
  {
    int u = t & 127, q = t >> 7, vb = q << 5;
    float m = -1e30f;
    for (int v = vb; v < vb+32; ++v) m = fmaxf(m, ST[SW(v, u)]);
    float l = 0.f;
    for (int v = vb; v < vb+32; ++v) l += __expf(ST[SW(v, u)] - m);
    float m2 = -1e30f;
    for (int k = (vb >> 2); k < (vb >> 2) + 8; ++k) {
      const float4 x4 = *(const float4*)&ST[SWQ(u, k)];
      m2 = fmaxf(m2, fmaxf(fmaxf(x4.x, x4.y), fmaxf(x4.z, x4.w)));
    }
    float l2 = 0.f;
    for (int k = (vb >> 2); k < (vb >> 2) + 8; ++k) {
      const float4 x4 = *(const float4*)&ST[SWQ(u, k)];
      l2 += (__expf(x4.x-m2)+__expf(x4.y-m2)) + (__expf(x4.z-m2)+__expf(x4.w-m2));
    }
    pm[t] = m; pl[t] = l;
    pm2[t] = m2; pl2[t] = l2;
  }
  __syncthreads();
  if (t < 256) {
    int u = t & 127;
    const float* PM = (t < 128) ? pm : pm2;
    const float* PL = (t < 128) ? pl : pl2;
    float m = fmaxf(fmaxf(PM[u], PM[128+u]), fmaxf(PM[256+u], PM[384+u]));
    float l = PL[u]*__expf(PM[u]-m) + PL[128+u]*__expf(PM[128+u]-m)
            + PL[256+u]*__expf(PM[256+u]-m) + PL[384+u]*__expf(PM[384+u]-m);
    if (t < 128) { rmax[u] = m; rinv[u] = 1.f/l; }
    else         { cmax[u] = m; cinv[u] = 1.f/l; }
  }
  __syncthreads();

  // ---- P3: V partials, G fused (no 64 KB buffer) ----
  // accL[u] = sum_v m_relax(M_rl)[u,v] * M_lr[v,u]
  // accR[u] = sum_v (sum_du M_lr[u+du,v]) * M_rl[v,u]
  {
    int u = t & 127, q = t >> 7, vb = q << 5;
    float rmm[5], rii[5], cmb[5], cib[5];
    int rcl[5];
    #pragma unroll
    for (int d = 0; d < 5; ++d) {
      int uu = u - 2 + d;
      bool ok = (uu >= 0 && uu < 128);
      rmm[d] = ok ? rmax[uu] : 1e30f;
      rii[d] = ok ? rinv[uu] : 0.f;
      cmb[d] = ok ? cmax[uu] : 1e30f;
      cib[d] = ok ? cinv[uu] : 0.f;
      rcl[d] = ok ? uu : u;
    }
    float accL = 0.f, accR = 0.f;
    for (int v = vb; v < vb+32; ++v) {
      float s = ST[SW(v, u)];
      float clr = __expf(s - cmax[v]) * cinv[v];        // M_lr[v,u]
      float R = __expf(s - rmm[2]) * rii[2];
      R += __expf(ST[SW(v, rcl[0])] - rmm[0]) * rii[0];
      R += __expf(ST[SW(v, rcl[1])] - rmm[1]) * rii[1];
      R += __expf(ST[SW(v, rcl[3])] - rmm[3]) * rii[3];
      R += __expf(ST[SW(v, rcl[4])] - rmm[4]) * rii[4];
      accL += R * clr;
      float s2 = ST[SW(u, v)];
      float mrl = __expf(s2 - rmax[v]) * rinv[v];       // M_rl[v,u]
      float Gs = __expf(s2 - cmb[2]) * cib[2];
      Gs += __expf(ST[SW(rcl[0], v)] - cmb[0]) * cib[0];
      Gs += __expf(ST[SW(rcl[1], v)] - cmb[1]) * cib[1];
      Gs += __expf(ST[SW(rcl[3], v)] - cmb[3]) * cib[3];
      Gs += __expf(ST[SW(rcl[4], v)] - cmb[4]) * cib[4];
      accR += Gs * mrl;
    }
    __syncthreads();   // P2 combine readers done before overwriting pm/pl
    pm[t] = accL; pl[t] = accR;
  }
  __syncthreads();
  if (t < 128) {
    float vsL = pm[t]+pm[128+t]+pm[256+t]+pm[384+t];
    float vsR = pl[t]+pl[128+t]+pl[256+t]+pl[384+t];
    Vl[t] = tanhf(5.f*vsL);
    Vr[t] = tanhf(5.f*vsR);
  }

  int ul = t & 63, c0 = (t >> 6) << 3;
  int c_ld = t >> 3, q_ld = (t & 7) << 2;     // chunk load: c 0..63, 4 v's

  // ---- P5: out_left = xl*(1-Vl) + (M_rl @ xr)*Vl, xr in 8 KB v-chunks ----
  {
    float acc0[8], acc1[8];
    #pragma unroll
    for (int j = 0; j < 8; ++j) { acc0[j]=0.f; acc1[j]=0.f; }
    float rm0 = rmax[ul], ri0 = rinv[ul], rm1 = rmax[ul+64], ri1 = rinv[ul+64];
    for (int cb = 0; cb < 4; ++cb) {
      int vb = cb << 5;
      __syncthreads();   // prev chunk consumed (and P3c/pm readers done)
      {
        const float4 r4 = *(const float4*)&XR[qbase + (size_t)c_ld*HW + vb + q_ld];
        CHB[(q_ld+0)*64+c_ld] = r4.x; CHB[(q_ld+1)*64+c_ld] = r4.y;
        CHB[(q_ld+2)*64+c_ld] = r4.z; CHB[(q_ld+3)*64+c_ld] = r4.w;
      }
      __syncthreads();
      for (int vv = 0; vv < 32; ++vv) {
        int v = vb + vv;
        float m0 = __expf(ST[SW(v, ul)]    - rm0) * ri0;
        float m1 = __expf(ST[SW(v, ul+64)] - rm1) * ri1;
        const float4 xa = *(const float4*)&CHB[vv*64 + c0];
        const float4 xb = *(const float4*)&CHB[vv*64 + c0 + 4];
        acc0[0]=fmaf(m0,xa.x,acc0[0]); acc0[1]=fmaf(m0,xa.y,acc0[1]);
        acc0[2]=fmaf(m0,xa.z,acc0[2]); acc0[3]=fmaf(m0,xa.w,acc0[3]);
        acc0[4]=fmaf(m0,xb.x,acc0[4]); acc0[5]=fmaf(m0,xb.y,acc0[5]);
        acc0[6]=fmaf(m0,xb.z,acc0[6]); acc0[7]=fmaf(m0,xb.w,acc0[7]);
        acc1[0]=fmaf(m1,xa.x,acc1[0]); acc1[1]=fmaf(m1,xa.y,acc1[1]);
        acc1[2]=fmaf(m1,xa.z,acc1[2]); acc1[3]=fmaf(m1,xa.w,acc1[3]);
        acc1[4]=fmaf(m1,xb.x,acc1[4]); acc1[5]=fmaf(m1,xb.y,acc1[5]);
        acc1[6]=fmaf(m1,xb.z,acc1[6]); acc1[7]=fmaf(m1,xb.w,acc1[7]);
      }
    }
    float vl0 = Vl[ul], vl1 = Vl[ul+64];
    #pragma unroll
    for (int j = 0; j < 8; ++j) {
      size_t o0 = qbase + (size_t)(c0+j)*HW + ul;
      outL[o0]    = XL[o0]   *(1.f-vl0) + acc0[j]*vl0;
      outL[o0+64] = XL[o0+64]*(1.f-vl1) + acc1[j]*vl1;
    }
  }

  // ---- P6: out_right = xr*(1-Vr) + (M_lr @ xl)*Vr, xl in 8 KB v-chunks ----
  {
    float acc0[8], acc1[8];
    #pragma unroll
    for (int j = 0; j < 8; ++j) { acc0[j]=0.f; acc1[j]=0.f; }
    float cm0 = cmax[ul], ci0 = cinv[ul], cm1 = cmax[ul+64], ci1 = cinv[ul+64];
    for (int cb = 0; cb < 4; ++cb) {
      int vb = cb << 5, qb = cb << 3;
      __syncthreads();
      {
        const float4 r4 = *(const float4*)&XL[qbase + (size_t)c_ld*HW + vb + q_ld];
        CHB[(q_ld+0)*64+c_ld] = r4.x; CHB[(q_ld+1)*64+c_ld] = r4.y;
        CHB[(q_ld+2)*64+c_ld] = r4.z; CHB[(q_ld+3)*64+c_ld] = r4.w;
      }
      __syncthreads();
      for (int lq = 0; lq < 8; ++lq) {
        const float4 s0 = *(const float4*)&ST[SWQ(ul,    qb+lq)];
        const float4 s1 = *(const float4*)&ST[SWQ(ul+64, qb+lq)];
        float sv0[4] = {s0.x, s0.y, s0.z, s0.w};
        float sv1[4] = {s1.x, s1.y, s1.z, s1.w};
        #pragma unroll
        for (int k = 0; k < 4; ++k) {
          float m0 = __expf(sv0[k] - cm0) * ci0;
          float m1 = __expf(sv1[k] - cm1) * ci1;
          const float4 xa0 = *(const float4*)&CHB[((lq<<2)+k)*64 + c0];
          const float4 xb0 = *(const float4*)&CHB[((lq<<2)+k)*64 + c0 + 4];
          acc0[0]=fmaf(m0,xa0.x,acc0[0]); acc0[1]=fmaf(m0,xa0.y,acc0[1]);
          acc0[2]=fmaf(m0,xa0.z,acc0[2]); acc0[3]=fmaf(m0,xa0.w,acc0[3]);
          acc0[4]=fmaf(m0,xb0.x,acc0[4]); acc0[5]=fmaf(m0,xb0.y,acc0[5]);
          acc0[6]=fmaf(m0,xb0.z,acc0[6]); acc0[7]=fmaf(m0,xb0.w,acc0[7]);
          acc1[0]=fmaf(m1,xa0.x,acc1[0]); acc1[1]=fmaf(m1,xa0.y,acc1[1]);
          acc1[2]=fmaf(m1,xa0.z,acc1[2]); acc1[3]=fmaf(m1,xa0.w,acc1[3]);
          acc1[4]=fmaf(m1,xb0.x,acc1[4]); acc1[5]=fmaf(m1,xb0.y,acc1[5]);
          acc1[6]=fmaf(m1,xb0.z,acc1[6]); acc1[7]=fmaf(m1,xb0.w,acc1[7]);
        }
      }
    }
    float vr0 = Vr[ul], vr1 = Vr[ul+64];
    #pragma unroll
    for (int j = 0; j < 8; ++j) {
      size_t o0 = qbase + (size_t)(c0+j)*HW + ul;
      outR[o0]    = XR[o0]   *(1.f-vr0) + acc0[j]*vr0;
      outR[o0+64] = XR[o0+64]*(1.f-vr1) + acc1[j]*vr1;
    }
  }
}

extern "C" void kernel_launch(void* const* d_in, const int* in_sizes, int n_in,
                              void* d_out, int out_size, void* d_ws, size_t ws_size,
                              hipStream_t stream) {
  const float* xL    = (const float*)d_in[0];
  const float* xR    = (const float*)d_in[1];
  const float* gamma = (const float*)d_in[2];
  const float* beta  = (const float*)d_in[3];
  const float* rw1   = (const float*)d_in[4];
  const float* rb1   = (const float*)d_in[5];
  const float* rw2   = (const float*)d_in[6];
  const float* rb2   = (const float*)d_in[7];
  const float* qw    = (const float*)d_in[8];
  const float* qb    = (const float*)d_in[9];
  const float* kw    = (const float*)d_in[10];
  const float* kb    = (const float*)d_in[11];
  float* out = (float*)d_out;
  char* ws = (char*)d_ws;

  const size_t BUF = (size_t)BB*CH_N*HW*4;   // 33,554,432 bytes
  float* y1   = (float*)(ws);
  float* y2L  = (float*)(ws + BUF);
  float* y2R  = (float*)(ws + 2*BUF);
  float* sums = (float*)(ws + 3*BUF);      // 256 floats
  float* ss   = sums + 256;                // 256 floats

  hipMemsetAsync(sums, 0, 1024, stream);
  k_stats<<<512, 256, 0, stream>>>(xL, xR, sums);
  k_finalize<<<1, 128, 0, stream>>>(sums, gamma, beta, ss);

  dim3 cg(64, 4, 8);
  k_conv<0><<<cg, 256, 0, stream>>>(xL, xL, rw1, rb1, ss,       y1);
  k_conv<1><<<cg, 256, 0, stream>>>(y1, xL, rw2, rb2, ss,       y2L);
  k_conv<0><<<cg, 256, 0, stream>>>(xR, xR, rw1, rb1, ss + 128, y1);
  k_conv<1><<<cg, 256, 0, stream>>>(y1, xR, rw2, rb2, ss + 128, y2R);

  k_qk<<<1024, 256, 0, stream>>>(y2L, qw, qb);
  k_qk<<<1024, 256, 0, stream>>>(y2R, kw, kb);

  const int SMEM = 19200 * 4;   // 76,800 B -> 2 blocks/CU
  hipFuncSetAttribute((const void*)k_pam, hipFuncAttributeMaxDynamicSharedMemorySize, SMEM);
  k_pam<<<1024, 512, SMEM, stream>>>(y2L, y2R, xL, xR, out, out + (size_t)BB*CH_N*HW);
}

// Round 6
// 585.527 us; speedup vs baseline: 1.1963x; 1.0459x over previous
//
#include <hip/hip_runtime.h>

#define CH_N 64
#define HH 128
#define WW 128
#define BB 8
#define HW (HH*WW)

// ---------------- BN stats: per-channel partial sums (atomics) ----------------
__global__ __launch_bounds__(256) void k_stats(const float* __restrict__ xL,
                                               const float* __restrict__ xR,
                                               float* __restrict__ sums) {
  int blk = blockIdx.x;                 // 512 blocks: img(2) x c(64) x slice(4)
  int img = blk >> 8, c = (blk >> 2) & 63, s = blk & 3;
  const float* x = img ? xR : xL;
  float sm = 0.f, sq = 0.f;
  for (int n = 2*s; n < 2*s+2; ++n) {
    const float4* p = (const float4*)(x + ((size_t)(n*64+c))*HW);
    for (int i = threadIdx.x; i < 4096; i += 256) {
      float4 v = p[i];
      sm += (v.x+v.y)+(v.z+v.w);
      sq += (v.x*v.x+v.y*v.y)+(v.z*v.z+v.w*v.w);
    }
  }
  #pragma unroll
  for (int o = 32; o > 0; o >>= 1) { sm += __shfl_down(sm, o); sq += __shfl_down(sq, o); }
  __shared__ float rs[2][4];
  int wid = threadIdx.x >> 6;
  if ((threadIdx.x & 63) == 0) { rs[0][wid] = sm; rs[1][wid] = sq; }
  __syncthreads();
  if (threadIdx.x == 0) {
    sm = (rs[0][0]+rs[0][1])+(rs[0][2]+rs[0][3]);
    sq = (rs[1][0]+rs[1][1])+(rs[1][2]+rs[1][3]);
    atomicAdd(&sums[(img*64+c)*2+0], sm);
    atomicAdd(&sums[(img*64+c)*2+1], sq);
  }
}

__global__ __launch_bounds__(128) void k_finalize(const float* __restrict__ sums,
                                                  const float* __restrict__ gamma,
                                                  const float* __restrict__ beta,
                                                  float* __restrict__ ss) {
  int t = threadIdx.x;
  if (t < 128) {
    int c = t & 63;
    float sm = sums[t*2], sq = sums[t*2+1];
    float mean = sm * (1.f/131072.f);
    float var  = sq * (1.f/131072.f) - mean*mean;
    float scale = gamma[c] * rsqrtf(var + 1e-5f);
    ss[t*2+0] = scale;
    ss[t*2+1] = beta[c] - mean*scale;
  }
}

// ---------------- grouped 3x3 conv, pad=1 ----------------
template<int MODE>
__global__ __launch_bounds__(256) void k_conv(const float* __restrict__ in,
                                              const float* __restrict__ xres,
                                              const float* __restrict__ w,
                                              const float* __restrict__ bias,
                                              const float* __restrict__ ss,
                                              float* __restrict__ out) {
  __shared__ float in_t[16][18][20];
  __shared__ float w_t[16][192];   // [oc][ic*12 + k]
  int tile = blockIdx.x, g = blockIdx.y, n = blockIdx.z;
  int x0 = (tile & 7) << 4, y0 = (tile >> 3) << 4;
  int t = threadIdx.x;

  for (int idx = t; idx < 2304; idx += 256) {
    int oc = idx/144, r = idx%144, ic = r/9, k = r%9;
    w_t[oc][ic*12+k] = w[(g*16+oc)*144 + r];
  }
  for (int idx = t; idx < 16*18*18; idx += 256) {
    int ic = idx/324, r2 = idx%324, ry = r2/18, rx = r2%18;
    int gy = y0-1+ry, gx = x0-1+rx;
    int c = g*16+ic;
    float v = 0.f;
    if (gy >= 0 && gy < 128 && gx >= 0 && gx < 128) {
      v = in[((size_t)(n*64+c)*128 + gy)*128 + gx];
      if (MODE == 0) v = v*ss[c*2] + ss[c*2+1];
    }
    in_t[ic][ry][rx] = v;
  }
  __syncthreads();

  int oc = t >> 4, sub = t & 15;
  int sy = (sub >> 2) << 2, sx = (sub & 3) << 2;
  float acc[4][4];
  float bv = bias[g*16+oc];
  #pragma unroll
  for (int i = 0; i < 4; ++i)
    #pragma unroll
    for (int j = 0; j < 4; ++j) acc[i][j] = bv;

  for (int ic = 0; ic < 16; ++ic) {
    float win[6][6];
    #pragma unroll
    for (int r = 0; r < 6; ++r) {
      const float4 wa = *(const float4*)&in_t[ic][sy+r][sx];
      const float2 wb = *(const float2*)&in_t[ic][sy+r][sx+4];
      win[r][0]=wa.x; win[r][1]=wa.y; win[r][2]=wa.z; win[r][3]=wa.w;
      win[r][4]=wb.x; win[r][5]=wb.y;
    }
    const float4 w0 = *(const float4*)&w_t[oc][ic*12];
    const float4 w1 = *(const float4*)&w_t[oc][ic*12+4];
    const float  w8 = w_t[oc][ic*12+8];
    float wv[9] = {w0.x,w0.y,w0.z,w0.w,w1.x,w1.y,w1.z,w1.w,w8};
    #pragma unroll
    for (int i = 0; i < 4; ++i)
      #pragma unroll
      for (int j = 0; j < 4; ++j) {
        float a = acc[i][j];
        #pragma unroll
        for (int ky = 0; ky < 3; ++ky)
          #pragma unroll
          for (int kx = 0; kx < 3; ++kx)
            a = fmaf(win[i+ky][j+kx], wv[ky*3+kx], a);
        acc[i][j] = a;
      }
  }

  int c = g*16+oc;
  #pragma unroll
  for (int i = 0; i < 4; ++i) {
    int oy = y0+sy+i;
    size_t rowbase = ((size_t)(n*64+c)*128 + oy)*128;
    #pragma unroll
    for (int j = 0; j < 4; ++j) {
      int ox = x0+sx+j;
      float v = acc[i][j];
      if (MODE == 0) { v = v > 0.f ? v : 0.1f*v; }
      else           { v += xres[rowbase+ox]*ss[c*2] + ss[c*2+1]; }
      out[rowbase+ox] = v;
    }
  }
}

// ---------------- grouped 1x1 conv + row-mean subtract (in-place) ----------------
__global__ __launch_bounds__(256) void k_qk(float* __restrict__ y2,
                                            const float* __restrict__ w,
                                            const float* __restrict__ bias) {
  __shared__ float row[64][128];
  __shared__ float wt[64][16];
  __shared__ float bt[64];
  int b = blockIdx.x >> 7, h = blockIdx.x & 127;
  int t = threadIdx.x;
  for (int idx = t; idx < 1024; idx += 256) wt[idx>>4][idx&15] = w[idx];
  if (t < 64) bt[t] = bias[t];
  __syncthreads();
  size_t base = ((size_t)(b*64)*128 + h)*128;   // + c*HW + u
  for (int idx = t; idx < 2048; idx += 256) {
    int c = idx >> 5, u4 = (idx & 31) << 2;
    *(float4*)&row[c][u4] = *(const float4*)&y2[base + (size_t)c*HW + u4];
  }
  __syncthreads();
  int u0 = (t & 31) << 2, oc0 = (t >> 5) << 3;
  int g = oc0 >> 4;
  float acc[8][4];
  #pragma unroll
  for (int j = 0; j < 8; ++j) {
    float b0 = bt[oc0+j];
    acc[j][0]=b0; acc[j][1]=b0; acc[j][2]=b0; acc[j][3]=b0;
  }
  for (int ic = 0; ic < 16; ++ic) {
    const float4 iv = *(const float4*)&row[g*16+ic][u0];
    #pragma unroll
    for (int j = 0; j < 8; ++j) {
      float wv = wt[oc0+j][ic];
      acc[j][0] = fmaf(wv, iv.x, acc[j][0]);
      acc[j][1] = fmaf(wv, iv.y, acc[j][1]);
      acc[j][2] = fmaf(wv, iv.z, acc[j][2]);
      acc[j][3] = fmaf(wv, iv.w, acc[j][3]);
    }
  }
  #pragma unroll
  for (int j = 0; j < 8; ++j) {
    float s = (acc[j][0]+acc[j][1])+(acc[j][2]+acc[j][3]);
    #pragma unroll
    for (int o = 16; o > 0; o >>= 1) s += __shfl_xor(s, o, 32);
    float mean = s * (1.f/128.f);
    float4 ov = make_float4(acc[j][0]-mean, acc[j][1]-mean, acc[j][2]-mean, acc[j][3]-mean);
    *(float4*)&y2[base + (size_t)(oc0+j)*HW + u0] = ov;
  }
}

// ---------------- PAM core: one block per (b,h) row, ~78 KB LDS -> 2 blk/CU ----
// Before transform: ST[SW(v,u)] = score[u][v].
// After transform:  ST[SW(v,u)] = M_rl[u,v] = exp(s_uv - rmax_u)*rinv_u.
// M_lr[a,b] = M_rl[b,a] * Pu[b] * Qv[a],  Pu[u] = l_u*exp(rmax_u - m*),
// Qv[v] = exp(m* - cmax_v)*cinv_v,  m* = global max.
__device__ __forceinline__ int SW(int r, int c) {
  return (r << 7) + (((c >> 2) ^ (r & 31)) << 2) + (c & 3);
}
__device__ __forceinline__ int SWQ(int r, int q) {
  return (r << 7) + ((q ^ (r & 31)) << 2);
}

__global__ __launch_bounds__(512, 4) void k_pam(const float* __restrict__ Q,
                                                const float* __restrict__ K,
                                                const float* __restrict__ XL,
                                                const float* __restrict__ XR,
                                                float* __restrict__ outL,
                                                float* __restrict__ outR) {
  extern __shared__ float smp[];
  float* ST   = smp;            // 16384 floats, swizzled score -> M_rl
  float* CHB  = smp + 16384;    // 2048 floats: QK chunks / x chunks / scratch
  float* rmax = smp + 18432;
  float* rinv = rmax + 128;
  float* cmax = rmax + 256;
  float* cinv = rmax + 384;
  float* Vl   = rmax + 512;
  float* Vr   = rmax + 640;
  float* Pu   = rmax + 768;
  float* Qv   = rmax + 896;
  float* ms   = rmax + 1024;    // [0] = global max
  float* pm   = CHB;            // P2/P3 partial scratch overlaps chunk buffer
  float* pl   = CHB + 512;
  float* pm2  = CHB + 1024;
  float* pl2  = CHB + 1536;

  int t = threadIdx.x;
  int b = blockIdx.x >> 7, h = blockIdx.x & 127;
  size_t qbase = ((size_t)(b*64)*128 + h)*128;   // + c*HW + u

  // ---- P1: score -> ST (swizzled), Q/K staged through 8 KB chunks of 8 ch ----
  {
    int u0 = (t & 31) << 2, v0 = (t >> 5) << 3;
    float a0[8], a1[8], a2[8], a3[8];
    #pragma unroll
    for (int j = 0; j < 8; ++j) { a0[j]=0.f; a1[j]=0.f; a2[j]=0.f; a3[j]=0.f; }
    int half = t >> 8;               // 0 = Q, 1 = K
    int cl_ld = (t >> 5) & 7;
    int u4_ld = (t & 31) << 2;
    const float* src = half ? K : Q;
    for (int cb = 0; cb < 8; ++cb) {
      __syncthreads();   // previous chunk fully consumed
      *(float4*)&CHB[half*1024 + cl_ld*128 + u4_ld] =
        *(const float4*)&src[qbase + (size_t)(cb*8 + cl_ld)*HW + u4_ld];
      __syncthreads();
      #pragma unroll
      for (int cl = 0; cl < 8; ++cl) {
        const float4 qv = *(const float4*)&CHB[cl*128 + u0];
        const float4 k0 = *(const float4*)&CHB[1024 + cl*128 + v0];
        const float4 k1 = *(const float4*)&CHB[1024 + cl*128 + v0 + 4];
        float kk[8] = {k0.x,k0.y,k0.z,k0.w,k1.x,k1.y,k1.z,k1.w};
        #pragma unroll
        for (int j = 0; j < 8; ++j) {
          float kv = kk[j];
          a0[j] = fmaf(qv.x, kv, a0[j]);
          a1[j] = fmaf(qv.y, kv, a1[j]);
          a2[j] = fmaf(qv.z, kv, a2[j]);
          a3[j] = fmaf(qv.w, kv, a3[j]);
        }
      }
    }
    #pragma unroll
    for (int j = 0; j < 8; ++j) {
      int r = v0 + j;
      *(float4*)&ST[SWQ(r, u0 >> 2)] = make_float4(a0[j], a1[j], a2[j], a3[j]);
    }
  }
  __syncthreads();

  // ---- P2: row stats (over v, fixed u) + col stats (over u, fixed v) ----
  {
    int u = t & 127, q = t >> 7, vb = q << 5;
    float m = -1e30f;
    for (int v = vb; v < vb+32; ++v) m = fmaxf(m, ST[SW(v, u)]);
    float l = 0.f;
    for (int v = vb; v < vb+32; ++v) l += __expf(ST[SW(v, u)] - m);
    float m2 = -1e30f;
    for (int k = (vb >> 2); k < (vb >> 2) + 8; ++k) {
      const float4 x4 = *(const float4*)&ST[SWQ(u, k)];
      m2 = fmaxf(m2, fmaxf(fmaxf(x4.x, x4.y), fmaxf(x4.z, x4.w)));
    }
    float l2 = 0.f;
    for (int k = (vb >> 2); k < (vb >> 2) + 8; ++k) {
      const float4 x4 = *(const float4*)&ST[SWQ(u, k)];
      l2 += (__expf(x4.x-m2)+__expf(x4.y-m2)) + (__expf(x4.z-m2)+__expf(x4.w-m2));
    }
    pm[t] = m; pl[t] = l;
    pm2[t] = m2; pl2[t] = l2;
  }
  __syncthreads();
  if (t < 256) {
    int u = t & 127;
    const float* PM = (t < 128) ? pm : pm2;
    const float* PL = (t < 128) ? pl : pl2;
    float m = fmaxf(fmaxf(PM[u], PM[128+u]), fmaxf(PM[256+u], PM[384+u]));
    float l = PL[u]*__expf(PM[u]-m) + PL[128+u]*__expf(PM[128+u]-m)
            + PL[256+u]*__expf(PM[256+u]-m) + PL[384+u]*__expf(PM[384+u]-m);
    if (t < 128) { rmax[u] = m; rinv[u] = 1.f/l; }
    else         { cmax[u] = m; cinv[u] = 1.f/l; }
  }
  __syncthreads();

  // ---- global max m* (one wave) ----
  if (t < 64) {
    float m = fmaxf(rmax[t], rmax[t+64]);
    #pragma unroll
    for (int o = 32; o > 0; o >>= 1) m = fmaxf(m, __shfl_down(m, o));
    if (t == 0) ms[0] = m;
  }
  __syncthreads();

  // ---- Pu/Qv + in-place transform ST -> M_rl ----
  {
    float ms0 = ms[0];
    if (t < 128)      Pu[t] = __expf(rmax[t] - ms0) / rinv[t];
    else if (t < 256) { int v = t - 128; Qv[v] = __expf(ms0 - cmax[v]) * cinv[v]; }
    int u = t & 127, q = t >> 7;
    float ru = rmax[u], ri = rinv[u];
    for (int v = (q << 5); v < (q << 5) + 32; ++v) {
      int a = SW(v, u);
      ST[a] = __expf(ST[a] - ru) * ri;
    }
  }
  __syncthreads();

  // ---- P3: V partials (exp-free) ----
  {
    int u = t & 127, q = t >> 7, vb = q << 5;
    int rcl[5]; float wL[5], qvd[5];
    #pragma unroll
    for (int d = 0; d < 5; ++d) {
      int uu = u - 2 + d;
      bool ok = (uu >= 0 && uu < 128);
      rcl[d] = ok ? uu : u;
      wL[d]  = ok ? 1.f : 0.f;
      qvd[d] = ok ? Qv[uu] : 0.f;
    }
    float pu_u = Pu[u];
    float accL = 0.f, accR = 0.f;
    for (int v = vb; v < vb+32; ++v) {
      float rr0 = ST[SW(v, rcl[0])], rr1 = ST[SW(v, rcl[1])];
      float rr2 = ST[SW(v, u)];
      float rr3 = ST[SW(v, rcl[3])], rr4 = ST[SW(v, rcl[4])];
      float R = rr2 + (wL[0]*rr0 + wL[1]*rr1) + (wL[3]*rr3 + wL[4]*rr4);
      accL = fmaf(R * rr2, Qv[v], accL);
      float cc0 = ST[SW(rcl[0], v)], cc1 = ST[SW(rcl[1], v)];
      float cc2 = ST[SW(u, v)];
      float cc3 = ST[SW(rcl[3], v)], cc4 = ST[SW(rcl[4], v)];
      float G = cc2*qvd[2] + (cc0*qvd[0] + cc1*qvd[1]) + (cc3*qvd[3] + cc4*qvd[4]);
      accR = fmaf(G * cc2, Pu[v], accR);
    }
    accL *= pu_u;
    __syncthreads();   // P2 combine readers done before overwriting pm/pl
    pm[t] = accL; pl[t] = accR;
  }
  __syncthreads();
  if (t < 128) {
    float vsL = pm[t]+pm[128+t]+pm[256+t]+pm[384+t];
    float vsR = pl[t]+pl[128+t]+pl[256+t]+pl[384+t];
    Vl[t] = tanhf(5.f*vsL);
    Vr[t] = tanhf(5.f*vsR);
  }

  int ul = t & 63, c0 = (t >> 6) << 3;
  int c_ld = t >> 3, q_ld = (t & 7) << 2;     // chunk load: c 0..63, 4 v's

  // ---- P5: out_left = xl*(1-Vl) + (M_rl @ xr)*Vl, xr in 8 KB v-chunks ----
  {
    float acc0[8], acc1[8];
    #pragma unroll
    for (int j = 0; j < 8; ++j) { acc0[j]=0.f; acc1[j]=0.f; }
    for (int cb = 0; cb < 4; ++cb) {
      int vb = cb << 5;
      __syncthreads();   // prev chunk consumed (and Vl/Vr readers done)
      {
        const float4 r4 = *(const float4*)&XR[qbase + (size_t)c_ld*HW + vb + q_ld];
        CHB[(q_ld+0)*64+c_ld] = r4.x; CHB[(q_ld+1)*64+c_ld] = r4.y;
        CHB[(q_ld+2)*64+c_ld] = r4.z; CHB[(q_ld+3)*64+c_ld] = r4.w;
      }
      __syncthreads();
      for (int vv = 0; vv < 32; ++vv) {
        int v = vb + vv;
        float m0 = ST[SW(v, ul)];
        float m1 = ST[SW(v, ul+64)];
        const float4 xa = *(const float4*)&CHB[vv*64 + c0];
        const float4 xb = *(const float4*)&CHB[vv*64 + c0 + 4];
        acc0[0]=fmaf(m0,xa.x,acc0[0]); acc0[1]=fmaf(m0,xa.y,acc0[1]);
        acc0[2]=fmaf(m0,xa.z,acc0[2]); acc0[3]=fmaf(m0,xa.w,acc0[3]);
        acc0[4]=fmaf(m0,xb.x,acc0[4]); acc0[5]=fmaf(m0,xb.y,acc0[5]);
        acc0[6]=fmaf(m0,xb.z,acc0[6]); acc0[7]=fmaf(m0,xb.w,acc0[7]);
        acc1[0]=fmaf(m1,xa.x,acc1[0]); acc1[1]=fmaf(m1,xa.y,acc1[1]);
        acc1[2]=fmaf(m1,xa.z,acc1[2]); acc1[3]=fmaf(m1,xa.w,acc1[3]);
        acc1[4]=fmaf(m1,xb.x,acc1[4]); acc1[5]=fmaf(m1,xb.y,acc1[5]);
        acc1[6]=fmaf(m1,xb.z,acc1[6]); acc1[7]=fmaf(m1,xb.w,acc1[7]);
      }
    }
    float vl0 = Vl[ul], vl1 = Vl[ul+64];
    #pragma unroll
    for (int j = 0; j < 8; ++j) {
      size_t o0 = qbase + (size_t)(c0+j)*HW + ul;
      outL[o0]    = XL[o0]   *(1.f-vl0) + acc0[j]*vl0;
      outL[o0+64] = XL[o0+64]*(1.f-vl1) + acc1[j]*vl1;
    }
  }

  // ---- P6: out_right = xr*(1-Vr) + (M_lr @ xl)*Vr, xl in 8 KB v-chunks ----
  // M_lr[u,v] = ST[SW(u,v)] * Pu[v] * Qv[u]
  {
    float acc0[8], acc1[8];
    #pragma unroll
    for (int j = 0; j < 8; ++j) { acc0[j]=0.f; acc1[j]=0.f; }
    float qv_u0 = Qv[ul], qv_u1 = Qv[ul+64];
    for (int cb = 0; cb < 4; ++cb) {
      int vb = cb << 5, qb = cb << 3;
      __syncthreads();
      {
        const float4 r4 = *(const float4*)&XL[qbase + (size_t)c_ld*HW + vb + q_ld];
        CHB[(q_ld+0)*64+c_ld] = r4.x; CHB[(q_ld+1)*64+c_ld] = r4.y;
        CHB[(q_ld+2)*64+c_ld] = r4.z; CHB[(q_ld+3)*64+c_ld] = r4.w;
      }
      __syncthreads();
      for (int lq = 0; lq < 8; ++lq) {
        const float4 s0 = *(const float4*)&ST[SWQ(ul,    qb+lq)];
        const float4 s1 = *(const float4*)&ST[SWQ(ul+64, qb+lq)];
        const float4 pu4 = *(const float4*)&Pu[(qb+lq) << 2];
        float sv0[4] = {s0.x, s0.y, s0.z, s0.w};
        float sv1[4] = {s1.x, s1.y, s1.z, s1.w};
        float pv[4]  = {pu4.x, pu4.y, pu4.z, pu4.w};
        #pragma unroll
        for (int k = 0; k < 4; ++k) {
          float m0 = sv0[k] * pv[k] * qv_u0;
          float m1 = sv1[k] * pv[k] * qv_u1;
          const float4 xa0 = *(const float4*)&CHB[((lq<<2)+k)*64 + c0];
          const float4 xb0 = *(const float4*)&CHB[((lq<<2)+k)*64 + c0 + 4];
          acc0[0]=fmaf(m0,xa0.x,acc0[0]); acc0[1]=fmaf(m0,xa0.y,acc0[1]);
          acc0[2]=fmaf(m0,xa0.z,acc0[2]); acc0[3]=fmaf(m0,xa0.w,acc0[3]);
          acc0[4]=fmaf(m0,xb0.x,acc0[4]); acc0[5]=fmaf(m0,xb0.y,acc0[5]);
          acc0[6]=fmaf(m0,xb0.z,acc0[6]); acc0[7]=fmaf(m0,xb0.w,acc0[7]);
          acc1[0]=fmaf(m1,xa0.x,acc1[0]); acc1[1]=fmaf(m1,xa0.y,acc1[1]);
          acc1[2]=fmaf(m1,xa0.z,acc1[2]); acc1[3]=fmaf(m1,xa0.w,acc1[3]);
          acc1[4]=fmaf(m1,xb0.x,acc1[4]); acc1[5]=fmaf(m1,xb0.y,acc1[5]);
          acc1[6]=fmaf(m1,xb0.z,acc1[6]); acc1[7]=fmaf(m1,xb0.w,acc1[7]);
        }
      }
    }
    float vr0 = Vr[ul], vr1 = Vr[ul+64];
    #pragma unroll
    for (int j = 0; j < 8; ++j) {
      size_t o0 = qbase + (size_t)(c0+j)*HW + ul;
      outR[o0]    = XR[o0]   *(1.f-vr0) + acc0[j]*vr0;
      outR[o0+64] = XR[o0+64]*(1.f-vr1) + acc1[j]*vr1;
    }
  }
}

extern "C" void kernel_launch(void* const* d_in, const int* in_sizes, int n_in,
                              void* d_out, int out_size, void* d_ws, size_t ws_size,
                              hipStream_t stream) {
  const float* xL    = (const float*)d_in[0];
  const float* xR    = (const float*)d_in[1];
  const float* gamma = (const float*)d_in[2];
  const float* beta  = (const float*)d_in[3];
  const float* rw1   = (const float*)d_in[4];
  const float* rb1   = (const float*)d_in[5];
  const float* rw2   = (const float*)d_in[6];
  const float* rb2   = (const float*)d_in[7];
  const float* qw    = (const float*)d_in[8];
  const float* qb    = (const float*)d_in[9];
  const float* kw    = (const float*)d_in[10];
  const float* kb    = (const float*)d_in[11];
  float* out = (float*)d_out;
  char* ws = (char*)d_ws;

  const size_t BUF = (size_t)BB*CH_N*HW*4;   // 33,554,432 bytes
  float* y1   = (float*)(ws);
  float* y2L  = (float*)(ws + BUF);
  float* y2R  = (float*)(ws + 2*BUF);
  float* sums = (float*)(ws + 3*BUF);      // 256 floats
  float* ss   = sums + 256;                // 256 floats

  hipMemsetAsync(sums, 0, 1024, stream);
  k_stats<<<512, 256, 0, stream>>>(xL, xR, sums);
  k_finalize<<<1, 128, 0, stream>>>(sums, gamma, beta, ss);

  dim3 cg(64, 4, 8);
  k_conv<0><<<cg, 256, 0, stream>>>(xL, xL, rw1, rb1, ss,       y1);
  k_conv<1><<<cg, 256, 0, stream>>>(y1, xL, rw2, rb2, ss,       y2L);
  k_conv<0><<<cg, 256, 0, stream>>>(xR, xR, rw1, rb1, ss + 128, y1);
  k_conv<1><<<cg, 256, 0, stream>>>(y1, xR, rw2, rb2, ss + 128, y2R);

  k_qk<<<1024, 256, 0, stream>>>(y2L, qw, qb);
  k_qk<<<1024, 256, 0, stream>>>(y2R, kw, kb);

  const int SMEM = 19464 * 4;   // 77,856 B -> 2 blocks/CU
  hipFuncSetAttribute((const void*)k_pam, hipFuncAttributeMaxDynamicSharedMemorySize, SMEM);
  k_pam<<<1024, 512, SMEM, stream>>>(y2L, y2R, xL, xR, out, out + (size_t)BB*CH_N*HW);
}